// Round 5
// baseline (284.389 us; speedup 1.0000x reference)
//
#include <hip/hip_runtime.h>
#include <hip/hip_bf16.h>
#include <cmath>

constexpr int KN   = 8;     // spline knots
constexpr int NPAR = 23;    // 3K-1
constexpr int DD   = 32;    // DIM
constexpr int HH   = 32;    // HID
constexpr float BND   = 3.0f;
constexpr float MINBW = 1e-3f;
constexpr float MIND  = 1e-3f;

#define TPB   256
#define ROWS  256    // batch rows per block
#define GDIMS 4      // output dims per block (8 groups cover 32)
#define HST   40     // sH row stride (shorts): 80B, 16B-aligned
#define PSTH  25     // sP row stride (halves)
#define RECB  8192   // per-layer packed weight record bytes

typedef __attribute__((ext_vector_type(8))) short short8;   // 8 bf16 (MFMA A/B frag)
typedef __attribute__((ext_vector_type(4))) float float4v;  // MFMA C/D frag

__device__ __forceinline__ short f2bf(float f) {
    unsigned u = __float_as_uint(f);
    u += 0x7fffu + ((u >> 16) & 1u);     // round-to-nearest-even
    return (short)(u >> 16);
}

__device__ __forceinline__ short2 pkbf(float a, float b) {
    union { __hip_bfloat162 v; short2 s; } u;
    u.v = __float22bfloat162_rn(make_float2(a, b));
    return u.s;
}
__device__ __forceinline__ int s2i(short2 v) {
    union { short2 s; int i; } u; u.s = v; return u.i;
}

__device__ __forceinline__ float fast_tanh(float x) {
    float ax = fminf(fabsf(x), 15.0f);
    float e  = __expf(2.0f * ax);
    float t  = 1.0f - 2.0f / (e + 1.0f);
    return copysignf(t, x);
}

__device__ __forceinline__ float softplus_f(float v) {
    return fmaxf(v, 0.0f) + log1pf(__expf(-fabsf(v)));
}

// Rational-quadratic spline for one scalar. p[0:8]=W logits, p[8:16]=H logits,
// p[16:23]=D logits (pre double-softplus). Returns z, writes logdet.
__device__ __forceinline__ float rqs_apply(float xv, const float* p, float& ldout) {
    float cw[KN + 1], ch[KN + 1], der[KN + 1];
    {
        float m = p[0];
#pragma unroll
        for (int k = 1; k < KN; ++k) m = fmaxf(m, p[k]);
        float t0[KN]; float s = 0.f;
#pragma unroll
        for (int k = 0; k < KN; ++k) { t0[k] = __expf(p[k] - m); s += t0[k]; }
        float inv = (2.0f * BND) / s;
        float e2[KN]; float s2 = 0.f;
#pragma unroll
        for (int k = 0; k < KN; ++k) { e2[k] = __expf(inv * (t0[k] - 1.0f)); s2 += e2[k]; }
        float fac = (1.0f - MINBW * KN) / s2;
        float c = 0.f;
        cw[0] = -BND;
#pragma unroll
        for (int k = 0; k < KN; ++k) { c += MINBW + fac * e2[k]; cw[k + 1] = 2.0f * BND * c - BND; }
        cw[KN] = BND;
    }
    {
        float m = p[KN];
#pragma unroll
        for (int k = 1; k < KN; ++k) m = fmaxf(m, p[KN + k]);
        float t0[KN]; float s = 0.f;
#pragma unroll
        for (int k = 0; k < KN; ++k) { t0[k] = __expf(p[KN + k] - m); s += t0[k]; }
        float inv = (2.0f * BND) / s;
        float e2[KN]; float s2 = 0.f;
#pragma unroll
        for (int k = 0; k < KN; ++k) { e2[k] = __expf(inv * (t0[k] - 1.0f)); s2 += e2[k]; }
        float fac = (1.0f - MINBW * KN) / s2;
        float c = 0.f;
        ch[0] = -BND;
#pragma unroll
        for (int k = 0; k < KN; ++k) { c += MINBW + fac * e2[k]; ch[k + 1] = 2.0f * BND * c - BND; }
        ch[KN] = BND;
    }
    der[0] = 1.0f; der[KN] = 1.0f;
#pragma unroll
    for (int k = 1; k < KN; ++k)
        der[k] = MIND + softplus_f(softplus_f(p[2 * KN + k - 1]));

    float xc = fminf(fmaxf(xv, -BND), BND);
    float in_cw = cw[0], in_w = cw[1] - cw[0];
    float in_ch = ch[0], in_h = ch[1] - ch[0];
    float d0 = der[0], d1 = der[1];
#pragma unroll
    for (int k = 1; k < KN; ++k) {
        bool c = (xc >= cw[k]);
        in_cw = c ? cw[k]            : in_cw;
        in_w  = c ? (cw[k+1]-cw[k])  : in_w;
        in_ch = c ? ch[k]            : in_ch;
        in_h  = c ? (ch[k+1]-ch[k])  : in_h;
        d0    = c ? der[k]           : d0;
        d1    = c ? der[k+1]         : d1;
    }

    float th    = (xc - in_cw) / in_w;
    float delta = in_h / in_w;
    float tt    = th * (1.0f - th);
    float th2   = th * th;
    float num   = in_h * (delta * th2 + d0 * tt);
    float den   = delta + (d0 + d1 - 2.0f * delta) * tt;
    float z     = in_ch + num / den;
    float omt   = 1.0f - th;
    float dnum  = delta * delta * (d1 * th2 + 2.0f * delta * tt + d0 * omt * omt);
    float ldv   = __logf(dnum) - 2.0f * __logf(den);

    bool inside = (xv >= -BND) && (xv <= BND);
    ldout = inside ? ldv : 0.0f;
    return inside ? z : xv;
}

// ---- prep: pack per-layer record: W1^T,W2^T,W3^T bf16 [n][k] (stride 40,
//      zero-padded) + b1,b2,b3 fp32. One block per layer. ----
extern "C" __global__ void __launch_bounds__(256)
k_prep(const float* __restrict__ w1, const float* __restrict__ b1,
       const float* __restrict__ w2, const float* __restrict__ b2,
       const float* __restrict__ w3, const float* __restrict__ b3,
       char* __restrict__ wbuf)
{
    const int l = blockIdx.x, tid = threadIdx.x;
    short* r1 = (short*)(wbuf + (size_t)l * RECB);
    short* r2 = r1 + 1280;
    short* r3 = r2 + 1280;
    float* f1 = (float*)(wbuf + (size_t)l * RECB + 7680);
    float* f2 = f1 + 32;
    float* f3 = f2 + 32;
    const float* g1 = w1 + (size_t)l * 992;    // [31][32]
    const float* g2 = w2 + (size_t)l * 1024;   // [32][32]
    const float* g3 = w3 + (size_t)l * 736;    // [32][23]
    for (int i = tid; i < 1280; i += 256) {
        int n = i / 40, k = i - 40 * n;
        r1[i] = (k < 31) ? f2bf(g1[k * 32 + n]) : (short)0;
        r2[i] = (k < 32) ? f2bf(g2[k * 32 + n]) : (short)0;
        r3[i] = (n < 23 && k < 32) ? f2bf(g3[k * 23 + n]) : (short)0;
    }
    if (tid < 32) { f1[tid] = b1[(size_t)l * 32 + tid]; f2[tid] = b2[(size_t)l * 32 + tid]; }
    if (tid < 24) f3[tid] = (tid < 23) ? b3[(size_t)l * 23 + tid] : 0.0f;
}

// Block: 256 rows x 4 output dims. 4 waves, wave wv owns rows [64wv,64wv+64)
// = 4 M-tiles. MFMA 16x16x32 bf16, K=32. sP/sH per-wave private -> spline
// needs no barrier. Weights pre-packed -> staging is a tiny vector memcpy.
extern "C" __global__ void __launch_bounds__(TPB, 6)
k_nsf(const float* __restrict__ x,
      const float* __restrict__ p0,
      const char* __restrict__ wbuf,
      float* __restrict__ zo, float* __restrict__ ldo, int B)
{
    __shared__ __align__(16) char  sRec[RECB];        // one layer record
    __shared__ __align__(16) short sH[4][16 * HST];   // per-wave C->A round-trip
    __shared__ _Float16 sP[ROWS * PSTH];              // per-wave-private P rows

    const short* sW1 = (const short*)sRec;
    const short* sW2 = sW1 + 1280;
    const short* sW3 = sW2 + 1280;
    const float* sB1 = (const float*)(sRec + 7680);
    const float* sB2 = sB1 + 32;
    const float* sB3 = sB2 + 32;

    const int tid  = threadIdx.x;
    const int lane = tid & 63;
    const int wv   = tid >> 6;
    const int q    = lane >> 4;
    const int ln   = lane & 15;
    const int g    = blockIdx.y;
    const int ly0  = GDIMS * g;
    const long long rowbase = (long long)blockIdx.x * ROWS;
    const long long row = rowbase + tid;

    // this thread's 4 spline inputs, one float4 load
    float xarr[GDIMS];
    {
        float4 xs = *(const float4*)(x + row * DD + ly0);
        xarr[0] = xs.x; xarr[1] = xs.y; xarr[2] = xs.z; xarr[3] = xs.w;
    }

    float zreg[GDIMS];
    float ldacc = 0.0f;

#pragma unroll
    for (int j = 0; j < GDIMS; ++j) {
        const int ly = ly0 + j;
        if (ly == 0) {
            float pr[NPAR];
#pragma unroll
            for (int k = 0; k < NPAR; ++k) pr[k] = p0[k];
            float ld;
            zreg[0] = rqs_apply(xarr[0], pr, ld);
            ldacc += ld;
            continue;
        }
        const int l = ly - 1;

        // ---- stage packed record (8192B = 512 int4) ----
        {
            const int4* src = (const int4*)(wbuf + (size_t)l * RECB);
            int4* dst = (int4*)sRec;
            dst[tid]       = src[tid];
            dst[tid + 256] = src[tid + 256];
        }
        __syncthreads();

        // hoist B-frags + biases (reused across 4 M-tiles)
        short8 w1b0 = *(const short8*)&sW1[ln * HST + q * 8];
        short8 w1b1 = *(const short8*)&sW1[(16 + ln) * HST + q * 8];
        short8 w2b0 = *(const short8*)&sW2[ln * HST + q * 8];
        short8 w2b1 = *(const short8*)&sW2[(16 + ln) * HST + q * 8];
        short8 w3b0 = *(const short8*)&sW3[ln * HST + q * 8];
        short8 w3b1 = *(const short8*)&sW3[(16 + ln) * HST + q * 8];
        float bv1a = sB1[ln], bv1b = sB1[16 + ln];
        float bv2a = sB2[ln], bv2b = sB2[16 + ln];
        float bv3a = sB3[ln], bv3b = (ln < 7) ? sB3[16 + ln] : 0.0f;

#pragma unroll
        for (int t = 0; t < 4; ++t) {
            const int m0 = 64 * wv + 16 * t;
            // ---- A1 from global x (fp32 -> bf16 packed cvt) ----
            const float4* xp = (const float4*)(x + (rowbase + m0 + ln) * DD + q * 8);
            float4 u = xp[0], v = xp[1];
            union { short8 s; int4 i; } au;
            au.i = make_int4(s2i(pkbf(u.x, u.y)), s2i(pkbf(u.z, u.w)),
                             s2i(pkbf(v.x, v.y)), s2i(pkbf(v.z, v.w)));
            short8 a = au.s;

            float4v c0 = {0.f,0.f,0.f,0.f}, c1 = {0.f,0.f,0.f,0.f};
            c0 = __builtin_amdgcn_mfma_f32_16x16x32_bf16(a, w1b0, c0, 0, 0, 0);
            c1 = __builtin_amdgcn_mfma_f32_16x16x32_bf16(a, w1b1, c1, 0, 0, 0);
            {
                short2 pA = pkbf(fast_tanh(c0[0] + bv1a), fast_tanh(c0[1] + bv1a));
                short2 pB = pkbf(fast_tanh(c0[2] + bv1a), fast_tanh(c0[3] + bv1a));
                short2 pC = pkbf(fast_tanh(c1[0] + bv1b), fast_tanh(c1[1] + bv1b));
                short2 pD = pkbf(fast_tanh(c1[2] + bv1b), fast_tanh(c1[3] + bv1b));
                short* hb = &sH[wv][q * 4 * HST];
                hb[0 * HST + ln] = pA.x; hb[1 * HST + ln] = pA.y;
                hb[2 * HST + ln] = pB.x; hb[3 * HST + ln] = pB.y;
                hb[0 * HST + 16 + ln] = pC.x; hb[1 * HST + 16 + ln] = pC.y;
                hb[2 * HST + 16 + ln] = pD.x; hb[3 * HST + 16 + ln] = pD.y;
            }
            // same-wave LDS write->read: compiler orders via lgkmcnt
            a = *(const short8*)&sH[wv][ln * HST + q * 8];
            float4v d0 = {0.f,0.f,0.f,0.f}, d1 = {0.f,0.f,0.f,0.f};
            d0 = __builtin_amdgcn_mfma_f32_16x16x32_bf16(a, w2b0, d0, 0, 0, 0);
            d1 = __builtin_amdgcn_mfma_f32_16x16x32_bf16(a, w2b1, d1, 0, 0, 0);
            {
                short2 pA = pkbf(fast_tanh(d0[0] + bv2a), fast_tanh(d0[1] + bv2a));
                short2 pB = pkbf(fast_tanh(d0[2] + bv2a), fast_tanh(d0[3] + bv2a));
                short2 pC = pkbf(fast_tanh(d1[0] + bv2b), fast_tanh(d1[1] + bv2b));
                short2 pD = pkbf(fast_tanh(d1[2] + bv2b), fast_tanh(d1[3] + bv2b));
                short* hb = &sH[wv][q * 4 * HST];
                hb[0 * HST + ln] = pA.x; hb[1 * HST + ln] = pA.y;
                hb[2 * HST + ln] = pB.x; hb[3 * HST + ln] = pB.y;
                hb[0 * HST + 16 + ln] = pC.x; hb[1 * HST + 16 + ln] = pC.y;
                hb[2 * HST + 16 + ln] = pD.x; hb[3 * HST + 16 + ln] = pD.y;
            }
            a = *(const short8*)&sH[wv][ln * HST + q * 8];
            float4v e0 = {0.f,0.f,0.f,0.f}, e1 = {0.f,0.f,0.f,0.f};
            e0 = __builtin_amdgcn_mfma_f32_16x16x32_bf16(a, w3b0, e0, 0, 0, 0);
            e1 = __builtin_amdgcn_mfma_f32_16x16x32_bf16(a, w3b1, e1, 0, 0, 0);
#pragma unroll
            for (int r = 0; r < 4; ++r) {
                int m = m0 + q * 4 + r;
                sP[m * PSTH + ln] = (_Float16)(e0[r] + bv3a);
                if (ln < 7) sP[m * PSTH + 16 + ln] = (_Float16)(e1[r] + bv3b);
            }
        }

        // ---- spline: thread tid -> row tid; sP rows written by OWN wave ----
        {
            float pr[NPAR];
#pragma unroll
            for (int k = 0; k < NPAR; ++k) pr[k] = (float)sP[tid * PSTH + k];
            float ld;
            zreg[j] = rqs_apply(xarr[j], pr, ld);
            ldacc += ld;
        }
        __syncthreads();   // protect sRec before next layer's staging
    }

    float4 zv = make_float4(zreg[0], zreg[1], zreg[2], zreg[3]);
    *(float4*)(zo + row * DD + ly0) = zv;
    unsafeAtomicAdd(&ldo[row], ldacc);
}

extern "C" void kernel_launch(void* const* d_in, const int* in_sizes, int n_in,
                              void* d_out, int out_size, void* d_ws, size_t ws_size,
                              hipStream_t stream) {
    const float* x  = (const float*)d_in[0];
    const float* p0 = (const float*)d_in[1];
    const float* w1 = (const float*)d_in[2];
    const float* b1 = (const float*)d_in[3];
    const float* w2 = (const float*)d_in[4];
    const float* b2 = (const float*)d_in[5];
    const float* w3 = (const float*)d_in[6];
    const float* b3 = (const float*)d_in[7];

    const int B = in_sizes[0] / DD;            // 65536
    float* zo  = (float*)d_out;
    float* ldo = zo + (size_t)B * DD;
    char* wbuf = (char*)d_ws;                  // 31 * 8192 B = 254 KB

    hipLaunchKernelGGL(k_prep, dim3(31), dim3(256), 0, stream,
                       w1, b1, w2, b2, w3, b3, wbuf);
    hipMemsetAsync(ldo, 0, (size_t)B * sizeof(float), stream);
    hipLaunchKernelGGL(k_nsf, dim3(B / ROWS, DD / GDIMS), dim3(TPB), 0, stream,
                       x, p0, wbuf, zo, ldo, B);
}

// Round 6
// 281.627 us; speedup vs baseline: 1.0098x; 1.0098x over previous
//
#include <hip/hip_runtime.h>
#include <hip/hip_bf16.h>
#include <cmath>

constexpr int KN   = 8;     // spline knots
constexpr int NPAR = 23;    // 3K-1
constexpr int DD   = 32;    // DIM
constexpr float BND   = 3.0f;
constexpr float MINBW = 1e-3f;
constexpr float MIND  = 1e-3f;

#define TPB   256
#define ROWS  256    // batch rows per block
#define GDIMS 4      // output dims per block (8 groups cover 32)
#define WST   40     // packed W row stride (shorts): 80B, 16B-aligned
#define PSTH  40     // sP row stride (halves): 80B, 16B-aligned
#define RECB  8192   // per-layer packed weight record bytes

typedef __attribute__((ext_vector_type(8))) short short8;      // 8 bf16 (MFMA A/B frag)
typedef __attribute__((ext_vector_type(4))) float float4v;     // MFMA C/D frag
typedef __attribute__((ext_vector_type(4))) _Float16 half4v;
typedef __attribute__((ext_vector_type(8))) _Float16 half8v;

__device__ __forceinline__ short f2bf(float f) {
    unsigned u = __float_as_uint(f);
    u += 0x7fffu + ((u >> 16) & 1u);     // round-to-nearest-even
    return (short)(u >> 16);
}

__device__ __forceinline__ int pkbf(float a, float b) {
    union { __hip_bfloat162 v; int i; } u;
    u.v = __float22bfloat162_rn(make_float2(a, b));
    return u.i;
}

__device__ __forceinline__ float fast_tanh(float x) {
    float ax = fminf(fabsf(x), 15.0f);
    float e  = __expf(2.0f * ax);
    float t  = 1.0f - 2.0f / (e + 1.0f);
    return copysignf(t, x);
}

__device__ __forceinline__ float softplus_f(float v) {
    return fmaxf(v, 0.0f) + log1pf(__expf(-fabsf(v)));
}

// Rational-quadratic spline for one scalar. p[0:8]=W logits, p[8:16]=H logits,
// p[16:23]=D logits (pre double-softplus). Returns z, writes logdet.
__device__ __forceinline__ float rqs_apply(float xv, const float* p, float& ldout) {
    float cw[KN + 1], ch[KN + 1], der[KN + 1];
    {
        float m = p[0];
#pragma unroll
        for (int k = 1; k < KN; ++k) m = fmaxf(m, p[k]);
        float t0[KN]; float s = 0.f;
#pragma unroll
        for (int k = 0; k < KN; ++k) { t0[k] = __expf(p[k] - m); s += t0[k]; }
        float inv = (2.0f * BND) / s;
        float e2[KN]; float s2 = 0.f;
#pragma unroll
        for (int k = 0; k < KN; ++k) { e2[k] = __expf(inv * (t0[k] - 1.0f)); s2 += e2[k]; }
        float fac = (1.0f - MINBW * KN) / s2;
        float c = 0.f;
        cw[0] = -BND;
#pragma unroll
        for (int k = 0; k < KN; ++k) { c += MINBW + fac * e2[k]; cw[k + 1] = 2.0f * BND * c - BND; }
        cw[KN] = BND;
    }
    {
        float m = p[KN];
#pragma unroll
        for (int k = 1; k < KN; ++k) m = fmaxf(m, p[KN + k]);
        float t0[KN]; float s = 0.f;
#pragma unroll
        for (int k = 0; k < KN; ++k) { t0[k] = __expf(p[KN + k] - m); s += t0[k]; }
        float inv = (2.0f * BND) / s;
        float e2[KN]; float s2 = 0.f;
#pragma unroll
        for (int k = 0; k < KN; ++k) { e2[k] = __expf(inv * (t0[k] - 1.0f)); s2 += e2[k]; }
        float fac = (1.0f - MINBW * KN) / s2;
        float c = 0.f;
        ch[0] = -BND;
#pragma unroll
        for (int k = 0; k < KN; ++k) { c += MINBW + fac * e2[k]; ch[k + 1] = 2.0f * BND * c - BND; }
        ch[KN] = BND;
    }
    der[0] = 1.0f; der[KN] = 1.0f;
#pragma unroll
    for (int k = 1; k < KN; ++k)
        der[k] = MIND + softplus_f(softplus_f(p[2 * KN + k - 1]));

    float xc = fminf(fmaxf(xv, -BND), BND);
    float in_cw = cw[0], in_w = cw[1] - cw[0];
    float in_ch = ch[0], in_h = ch[1] - ch[0];
    float d0 = der[0], d1 = der[1];
#pragma unroll
    for (int k = 1; k < KN; ++k) {
        bool c = (xc >= cw[k]);
        in_cw = c ? cw[k]            : in_cw;
        in_w  = c ? (cw[k+1]-cw[k])  : in_w;
        in_ch = c ? ch[k]            : in_ch;
        in_h  = c ? (ch[k+1]-ch[k])  : in_h;
        d0    = c ? der[k]           : d0;
        d1    = c ? der[k+1]         : d1;
    }

    float th    = (xc - in_cw) / in_w;
    float delta = in_h / in_w;
    float tt    = th * (1.0f - th);
    float th2   = th * th;
    float num   = in_h * (delta * th2 + d0 * tt);
    float den   = delta + (d0 + d1 - 2.0f * delta) * tt;
    float z     = in_ch + num / den;
    float omt   = 1.0f - th;
    float dnum  = delta * delta * (d1 * th2 + 2.0f * delta * tt + d0 * omt * omt);
    float ldv   = __logf(dnum) - 2.0f * __logf(den);

    bool inside = (xv >= -BND) && (xv <= BND);
    ldout = inside ? ldv : 0.0f;
    return inside ? z : xv;
}

// C-layout -> B-frag cross-lane transpose (no LDS). Inputs: two 16x16 C tiles
// (cA rows = out 0..15, cB rows = out 16..31, col = lane&15 = batch) plus
// per-quad bias float4s. Output: B-frag for next GEMM: lane(n,q) holds
// H[8q..8q+7] of batch col n. 4-round __shfl schedule (verified mapping).
__device__ __forceinline__ short8 xpose_h(float4v cA, float4v cB,
                                          float4 bA, float4 bB,
                                          int odd, int sl_a, int sl_b, bool qlow) {
    int a0 = pkbf(fast_tanh(cA[0] + bA.x), fast_tanh(cA[1] + bA.y));
    int a1 = pkbf(fast_tanh(cA[2] + bA.z), fast_tanh(cA[3] + bA.w));
    int b0 = pkbf(fast_tanh(cB[0] + bB.x), fast_tanh(cB[1] + bB.y));
    int b1 = pkbf(fast_tanh(cB[2] + bB.z), fast_tanh(cB[3] + bB.w));
    int p0 = odd ? b0 : a0, p1 = odd ? b1 : a1;
    int p2 = odd ? a0 : b0, p3 = odd ? a1 : b1;
    int g0 = __shfl(p0, sl_a, 64);
    int g1 = __shfl(p1, sl_a, 64);
    int g2 = __shfl(p2, sl_b, 64);
    int g3 = __shfl(p3, sl_b, 64);
    union { int4 i; short8 s; } u;
    u.i = qlow ? make_int4(g0, g1, g2, g3) : make_int4(g2, g3, g0, g1);
    return u.s;
}

// ---- prep: pack per-layer record: W1^T,W2^T,W3^T bf16 [out][in] stride 40
//      (zero-padded) + b1,b2,b3 fp32 (b3 padded to 32). One block per layer.
extern "C" __global__ void __launch_bounds__(256)
k_prep(const float* __restrict__ w1, const float* __restrict__ b1,
       const float* __restrict__ w2, const float* __restrict__ b2,
       const float* __restrict__ w3, const float* __restrict__ b3,
       char* __restrict__ wbuf)
{
    const int l = blockIdx.x, tid = threadIdx.x;
    short* r1 = (short*)(wbuf + (size_t)l * RECB);
    short* r2 = r1 + 1280;
    short* r3 = r2 + 1280;
    float* f1 = (float*)(wbuf + (size_t)l * RECB + 7680);
    float* f2 = f1 + 32;
    float* f3 = f2 + 32;
    const float* g1 = w1 + (size_t)l * 992;    // [31][32]
    const float* g2 = w2 + (size_t)l * 1024;   // [32][32]
    const float* g3 = w3 + (size_t)l * 736;    // [32][23]
    for (int i = tid; i < 1280; i += 256) {
        int n = i / WST, k = i - WST * n;
        r1[i] = (k < 31) ? f2bf(g1[k * 32 + n]) : (short)0;
        r2[i] = (k < 32) ? f2bf(g2[k * 32 + n]) : (short)0;
        r3[i] = (n < 23 && k < 32) ? f2bf(g3[k * 23 + n]) : (short)0;
    }
    if (tid < 32) { f1[tid] = b1[(size_t)l * 32 + tid]; f2[tid] = b2[(size_t)l * 32 + tid]; }
    if (tid < 32) f3[tid] = (tid < 23) ? b3[(size_t)l * 23 + tid] : 0.0f;
}

// Block: 256 rows x 4 output dims. 4 waves; wave wv owns rows [64wv,64wv+64)
// = 4 independent M... batch-col tiles. GEMMs computed as W^T (A) x X^T (B):
// C(out, batch). Inter-GEMM transform is register-only (__shfl), so the 4
// tile chains are fully independent -> ILP hides MFMA/tanh latency.
extern "C" __global__ void __launch_bounds__(TPB, 4)
k_nsf(const float* __restrict__ x,
      const float* __restrict__ p0,
      const char* __restrict__ wbuf,
      float* __restrict__ zo, float* __restrict__ ldo, int B)
{
    __shared__ __align__(16) char sRec[RECB];     // one layer record
    __shared__ _Float16 sP[ROWS * PSTH];          // spline params, per-wave rows

    const short* sW1 = (const short*)sRec;
    const short* sW2 = sW1 + 1280;
    const short* sW3 = sW1 + 2560;
    const float* sB1 = (const float*)(sRec + 7680);
    const float* sB2 = sB1 + 32;
    const float* sB3 = sB1 + 64;

    const int tid  = threadIdx.x;
    const int lane = tid & 63;
    const int wv   = tid >> 6;
    const int q    = lane >> 4;         // quad = r4 (C rows group / B k-group)
    const int ln   = lane & 15;         // batch col within tile
    const int qb   = q & 1;
    const bool qlow = (q < 2);
    const int s_even = ln + 32 * qb;
    const int s_odd  = s_even + 16;
    const int sl_a = qlow ? s_even : s_odd;
    const int sl_b = qlow ? s_odd  : s_even;
    const int g    = blockIdx.y;
    const int ly0  = GDIMS * g;
    const long long rowbase = (long long)blockIdx.x * ROWS;
    const long long row = rowbase + tid;

    // this thread's 4 spline inputs, one float4 load
    float xarr[GDIMS];
    {
        float4 xs = *(const float4*)(x + row * DD + ly0);
        xarr[0] = xs.x; xarr[1] = xs.y; xarr[2] = xs.z; xarr[3] = xs.w;
    }

    float zreg[GDIMS];
    float ldacc = 0.0f;

#pragma unroll
    for (int j = 0; j < GDIMS; ++j) {
        const int ly = ly0 + j;
        if (ly == 0) {
            float pr[NPAR];
#pragma unroll
            for (int k = 0; k < NPAR; ++k) pr[k] = p0[k];
            float ld;
            zreg[0] = rqs_apply(xarr[0], pr, ld);
            ldacc += ld;
            continue;
        }
        const int l = ly - 1;

        // ---- stage packed record (8192B = 512 int4) ----
        {
            const int4* src = (const int4*)(wbuf + (size_t)l * RECB);
            int4* dst = (int4*)sRec;
            dst[tid]       = src[tid];
            dst[tid + 256] = src[tid + 256];
        }
        __syncthreads();

        // A-frags: W^T rows = out dims (tileA: out 0..15 -> row ln,
        // tileB: out 16..31), k = 8q..8q+7. Biases per C-reg: out = 4q+r.
        short8 w1a = *(const short8*)&sW1[ln * WST + q * 8];
        short8 w1b = *(const short8*)&sW1[(16 + ln) * WST + q * 8];
        short8 w2a = *(const short8*)&sW2[ln * WST + q * 8];
        short8 w2b = *(const short8*)&sW2[(16 + ln) * WST + q * 8];
        short8 w3a = *(const short8*)&sW3[ln * WST + q * 8];
        short8 w3b = *(const short8*)&sW3[(16 + ln) * WST + q * 8];
        float4 bA1 = *(const float4*)&sB1[4 * q];
        float4 bB1 = *(const float4*)&sB1[16 + 4 * q];
        float4 bA2 = *(const float4*)&sB2[4 * q];
        float4 bB2 = *(const float4*)&sB2[16 + 4 * q];
        float4 bA3 = *(const float4*)&sB3[4 * q];
        float4 bB3 = *(const float4*)&sB3[16 + 4 * q];

#pragma unroll
        for (int t = 0; t < 4; ++t) {
            const int m0 = 64 * wv + 16 * t;
            // B1-frag: lane (n=ln, q) holds x[batch row m0+ln][8q..8q+7]
            const float4* xp = (const float4*)(x + (rowbase + m0 + ln) * DD + q * 8);
            float4 uu = xp[0], vv = xp[1];
            union { int4 i; short8 s; } au;
            au.i = make_int4(pkbf(uu.x, uu.y), pkbf(uu.z, uu.w),
                             pkbf(vv.x, vv.y), pkbf(vv.z, vv.w));

            float4v cA = {0.f,0.f,0.f,0.f}, cB = {0.f,0.f,0.f,0.f};
            cA = __builtin_amdgcn_mfma_f32_16x16x32_bf16(w1a, au.s, cA, 0, 0, 0);
            cB = __builtin_amdgcn_mfma_f32_16x16x32_bf16(w1b, au.s, cB, 0, 0, 0);
            short8 h1f = xpose_h(cA, cB, bA1, bB1, qb, sl_a, sl_b, qlow);

            float4v dA = {0.f,0.f,0.f,0.f}, dB = {0.f,0.f,0.f,0.f};
            dA = __builtin_amdgcn_mfma_f32_16x16x32_bf16(w2a, h1f, dA, 0, 0, 0);
            dB = __builtin_amdgcn_mfma_f32_16x16x32_bf16(w2b, h1f, dB, 0, 0, 0);
            short8 h2f = xpose_h(dA, dB, bA2, bB2, qb, sl_a, sl_b, qlow);

            float4v eA = {0.f,0.f,0.f,0.f}, eB = {0.f,0.f,0.f,0.f};
            eA = __builtin_amdgcn_mfma_f32_16x16x32_bf16(w3a, h2f, eA, 0, 0, 0);
            eB = __builtin_amdgcn_mfma_f32_16x16x32_bf16(w3b, h2f, eB, 0, 0, 0);

            // params: row = batch col (m0+ln), this lane holds params 4q+r
            // (eA) and 16+4q+r (eB; junk >22 lands in pad). Two b64 writes.
            half4v pv0, pv1;
            pv0[0] = (_Float16)(eA[0] + bA3.x); pv0[1] = (_Float16)(eA[1] + bA3.y);
            pv0[2] = (_Float16)(eA[2] + bA3.z); pv0[3] = (_Float16)(eA[3] + bA3.w);
            pv1[0] = (_Float16)(eB[0] + bB3.x); pv1[1] = (_Float16)(eB[1] + bB3.y);
            pv1[2] = (_Float16)(eB[2] + bB3.z); pv1[3] = (_Float16)(eB[3] + bB3.w);
            *(half4v*)&sP[(m0 + ln) * PSTH + 4 * q]      = pv0;
            *(half4v*)&sP[(m0 + ln) * PSTH + 16 + 4 * q] = pv1;
        }

        // ---- spline: thread tid -> row tid (written by OWN wave, lgkm-ordered)
        {
            half8v r0 = *(const half8v*)&sP[tid * PSTH];
            half8v r1 = *(const half8v*)&sP[tid * PSTH + 8];
            half8v r2 = *(const half8v*)&sP[tid * PSTH + 16];
            float pr[NPAR];
#pragma unroll
            for (int k = 0; k < 8; ++k) pr[k] = (float)r0[k];
#pragma unroll
            for (int k = 0; k < 8; ++k) pr[8 + k] = (float)r1[k];
#pragma unroll
            for (int k = 0; k < 7; ++k) pr[16 + k] = (float)r2[k];
            float ld;
            zreg[j] = rqs_apply(xarr[j], pr, ld);
            ldacc += ld;
        }
        __syncthreads();   // protect sRec before next layer's staging
    }

    float4 zv = make_float4(zreg[0], zreg[1], zreg[2], zreg[3]);
    *(float4*)(zo + row * DD + ly0) = zv;
    unsafeAtomicAdd(&ldo[row], ldacc);
}

extern "C" void kernel_launch(void* const* d_in, const int* in_sizes, int n_in,
                              void* d_out, int out_size, void* d_ws, size_t ws_size,
                              hipStream_t stream) {
    const float* x  = (const float*)d_in[0];
    const float* p0 = (const float*)d_in[1];
    const float* w1 = (const float*)d_in[2];
    const float* b1 = (const float*)d_in[3];
    const float* w2 = (const float*)d_in[4];
    const float* b2 = (const float*)d_in[5];
    const float* w3 = (const float*)d_in[6];
    const float* b3 = (const float*)d_in[7];

    const int B = in_sizes[0] / DD;            // 65536
    float* zo  = (float*)d_out;
    float* ldo = zo + (size_t)B * DD;
    char* wbuf = (char*)d_ws;                  // 31 * 8192 B = 254 KB

    hipLaunchKernelGGL(k_prep, dim3(31), dim3(256), 0, stream,
                       w1, b1, w2, b2, w3, b3, wbuf);
    hipMemsetAsync(ldo, 0, (size_t)B * sizeof(float), stream);
    hipLaunchKernelGGL(k_nsf, dim3(B / ROWS, DD / GDIMS), dim3(TPB), 0, stream,
                       x, p0, wbuf, zo, ldo, B);
}

// Round 8
// 181.154 us; speedup vs baseline: 1.5699x; 1.5546x over previous
//
#include <hip/hip_runtime.h>
#include <hip/hip_bf16.h>
#include <cmath>

constexpr int KN   = 8;     // spline knots
constexpr int NPAR = 23;    // 3K-1
constexpr int DD   = 32;    // DIM
constexpr float BND   = 3.0f;
constexpr float MINBW = 1e-3f;
constexpr float MIND  = 1e-3f;

#define TPB   256
#define ROWS  256    // batch rows per block
#define GDIMS 4      // output dims per block (8 groups cover 32)
#define WST   40     // packed W row stride (shorts): 80B, 16B-aligned
#define PSTH  24     // sP row stride (halves): 48B -> 16B-aligned, conflict-free
#define RECB  8192   // per-layer packed weight record bytes

typedef __attribute__((ext_vector_type(8))) short short8;      // 8 bf16 (MFMA A/B frag)
typedef __attribute__((ext_vector_type(4))) float float4v;     // MFMA C/D frag
typedef __attribute__((ext_vector_type(2))) __fp16 fp16x2;     // cvt_pkrtz result type
typedef __attribute__((ext_vector_type(8))) _Float16 half8v;

#define RCP(x) __builtin_amdgcn_rcpf(x)

__device__ __forceinline__ short f2bf(float f) {
    unsigned u = __float_as_uint(f);
    u += 0x7fffu + ((u >> 16) & 1u);     // round-to-nearest-even
    return (short)(u >> 16);
}

__device__ __forceinline__ int pkbf(float a, float b) {
    union { __hip_bfloat162 v; int i; } u;
    u.v = __float22bfloat162_rn(make_float2(a, b));
    return u.i;
}

// packed f32x2 -> f16x2 as raw int
__device__ __forceinline__ int pkh(float a, float b) {
    union { fp16x2 h; int i; } u;
    u.h = __builtin_amdgcn_cvt_pkrtz(a, b);
    return u.i;
}

// tanh = 1 - 2/(e^2x + 1): exact at both tails (exp->0 => -1, exp->inf => +1)
__device__ __forceinline__ float fast_tanh(float x) {
    float e = __expf(2.0f * x);
    return 1.0f - 2.0f * RCP(e + 1.0f);
}

// softplus for |v| <= ~8: e^v can't overflow, log(1+e^v) direct
__device__ __forceinline__ float softplus_fast(float v) {
    return __logf(1.0f + __expf(v));
}

// Rational-quadratic spline for one scalar. p[0:8]=W logits, p[8:16]=H logits,
// p[16:23]=D logits (pre double-softplus). Returns z, writes logdet.
// Logits are conditioner outputs, |p| small -> no softmax max-shift needed.
__device__ __forceinline__ float rqs_apply(float xv, const float* p, float& ldout) {
    float cw[KN + 1], ch[KN + 1], der[KN + 1];
    {
        float t0[KN]; float s = 0.f;
#pragma unroll
        for (int k = 0; k < KN; ++k) { t0[k] = __expf(p[k]); s += t0[k]; }
        float inv = (2.0f * BND) * RCP(s);          // Wu_k = inv * t0[k]
        float e2[KN]; float s2 = 0.f;
#pragma unroll
        for (int k = 0; k < KN; ++k) { e2[k] = __expf(inv * t0[k]); s2 += e2[k]; }
        float fac = (1.0f - MINBW * KN) * RCP(s2);
        float c = 0.f;
        cw[0] = -BND;
#pragma unroll
        for (int k = 0; k < KN; ++k) { c += MINBW + fac * e2[k]; cw[k + 1] = 2.0f * BND * c - BND; }
        cw[KN] = BND;
    }
    {
        float t0[KN]; float s = 0.f;
#pragma unroll
        for (int k = 0; k < KN; ++k) { t0[k] = __expf(p[KN + k]); s += t0[k]; }
        float inv = (2.0f * BND) * RCP(s);
        float e2[KN]; float s2 = 0.f;
#pragma unroll
        for (int k = 0; k < KN; ++k) { e2[k] = __expf(inv * t0[k]); s2 += e2[k]; }
        float fac = (1.0f - MINBW * KN) * RCP(s2);
        float c = 0.f;
        ch[0] = -BND;
#pragma unroll
        for (int k = 0; k < KN; ++k) { c += MINBW + fac * e2[k]; ch[k + 1] = 2.0f * BND * c - BND; }
        ch[KN] = BND;
    }
    der[0] = 1.0f; der[KN] = 1.0f;
#pragma unroll
    for (int k = 1; k < KN; ++k)
        der[k] = MIND + softplus_fast(softplus_fast(p[2 * KN + k - 1]));

    float xc = fminf(fmaxf(xv, -BND), BND);
    float in_cw = cw[0], in_w = cw[1] - cw[0];
    float in_ch = ch[0], in_h = ch[1] - ch[0];
    float d0 = der[0], d1 = der[1];
#pragma unroll
    for (int k = 1; k < KN; ++k) {
        bool c = (xc >= cw[k]);
        in_cw = c ? cw[k]            : in_cw;
        in_w  = c ? (cw[k+1]-cw[k])  : in_w;
        in_ch = c ? ch[k]            : in_ch;
        in_h  = c ? (ch[k+1]-ch[k])  : in_h;
        d0    = c ? der[k]           : d0;
        d1    = c ? der[k+1]         : d1;
    }

    float rw    = RCP(in_w);
    float th    = (xc - in_cw) * rw;
    float delta = in_h * rw;
    float tt    = th * (1.0f - th);
    float th2   = th * th;
    float num   = in_h * (delta * th2 + d0 * tt);
    float den   = delta + (d0 + d1 - 2.0f * delta) * tt;
    float z     = in_ch + num * RCP(den);
    float omt   = 1.0f - th;
    float dnum  = delta * delta * (d1 * th2 + 2.0f * delta * tt + d0 * omt * omt);
    float ldv   = __logf(dnum) - 2.0f * __logf(den);

    bool inside = (xv >= -BND) && (xv <= BND);
    ldout = inside ? ldv : 0.0f;
    return inside ? z : xv;
}

// C-layout -> B-frag cross-lane transpose (no LDS). 4-round __shfl schedule
// (mapping verified in R6; unchanged).
__device__ __forceinline__ short8 xpose_h(float4v cA, float4v cB,
                                          float4 bA, float4 bB,
                                          int odd, int sl_a, int sl_b, bool qlow) {
    int a0 = pkbf(fast_tanh(cA[0] + bA.x), fast_tanh(cA[1] + bA.y));
    int a1 = pkbf(fast_tanh(cA[2] + bA.z), fast_tanh(cA[3] + bA.w));
    int b0 = pkbf(fast_tanh(cB[0] + bB.x), fast_tanh(cB[1] + bB.y));
    int b1 = pkbf(fast_tanh(cB[2] + bB.z), fast_tanh(cB[3] + bB.w));
    int p0 = odd ? b0 : a0, p1 = odd ? b1 : a1;
    int p2 = odd ? a0 : b0, p3 = odd ? a1 : b1;
    int g0 = __shfl(p0, sl_a, 64);
    int g1 = __shfl(p1, sl_a, 64);
    int g2 = __shfl(p2, sl_b, 64);
    int g3 = __shfl(p3, sl_b, 64);
    union { int4 i; short8 s; } u;
    u.i = qlow ? make_int4(g0, g1, g2, g3) : make_int4(g2, g3, g0, g1);
    return u.s;
}

// ---- prep: blocks 0..30 pack per-layer records; blocks 31..94 zero ldo ----
extern "C" __global__ void __launch_bounds__(256)
k_prep(const float* __restrict__ w1, const float* __restrict__ b1,
       const float* __restrict__ w2, const float* __restrict__ b2,
       const float* __restrict__ w3, const float* __restrict__ b3,
       char* __restrict__ wbuf, float* __restrict__ ldo, int B)
{
    const int l = blockIdx.x, tid = threadIdx.x;
    if (l >= 31) {
        const int zb = l - 31;                 // 0..63
        const int chunk = B >> 6;              // floats per zero-block
        float4* dst = (float4*)(ldo + (size_t)zb * chunk);
        for (int i = tid; i < (chunk >> 2); i += 256)
            dst[i] = make_float4(0.f, 0.f, 0.f, 0.f);
        return;
    }
    short* r1 = (short*)(wbuf + (size_t)l * RECB);
    short* r2 = r1 + 1280;
    short* r3 = r2 + 1280;
    float* f1 = (float*)(wbuf + (size_t)l * RECB + 7680);
    float* f2 = f1 + 32;
    float* f3 = f2 + 32;
    const float* g1 = w1 + (size_t)l * 992;    // [31][32]
    const float* g2 = w2 + (size_t)l * 1024;   // [32][32]
    const float* g3 = w3 + (size_t)l * 736;    // [32][23]
    for (int i = tid; i < 1280; i += 256) {
        int n = i / WST, k = i - WST * n;
        r1[i] = (k < 31) ? f2bf(g1[k * 32 + n]) : (short)0;
        r2[i] = (k < 32) ? f2bf(g2[k * 32 + n]) : (short)0;
        r3[i] = (n < 23 && k < 32) ? f2bf(g3[k * 23 + n]) : (short)0;
    }
    if (tid < 32) { f1[tid] = b1[(size_t)l * 32 + tid]; f2[tid] = b2[(size_t)l * 32 + tid]; }
    if (tid < 32) f3[tid] = (tid < 23) ? b3[(size_t)l * 23 + tid] : 0.0f;
}

// Block: 256 rows x 4 output dims. 4 waves; GEMMs as W^T (A) x X^T (B), C in
// (out, batch); inter-GEMM transform register-only (__shfl). LDS 20.5KB ->
// 7 blocks/CU.
extern "C" __global__ void __launch_bounds__(TPB, 7)
k_nsf(const float* __restrict__ x,
      const float* __restrict__ p0,
      const char* __restrict__ wbuf,
      float* __restrict__ zo, float* __restrict__ ldo, int B)
{
    __shared__ __align__(16) char sRec[RECB];     // one layer record
    __shared__ __align__(16) _Float16 sP[ROWS * PSTH];   // spline params

    const short* sW1 = (const short*)sRec;
    const short* sW2 = sW1 + 1280;
    const short* sW3 = sW1 + 2560;
    const float* sB1 = (const float*)(sRec + 7680);
    const float* sB2 = sB1 + 32;
    const float* sB3 = sB1 + 64;

    const int tid  = threadIdx.x;
    const int lane = tid & 63;
    const int wv   = tid >> 6;
    const int q    = lane >> 4;         // quad
    const int ln   = lane & 15;         // batch col within tile
    const int qb   = q & 1;
    const bool qlow = (q < 2);
    const int s_even = ln + 32 * qb;
    const int s_odd  = s_even + 16;
    const int sl_a = qlow ? s_even : s_odd;
    const int sl_b = qlow ? s_odd  : s_even;
    const int g    = blockIdx.y;
    const int ly0  = GDIMS * g;
    const long long rowbase = (long long)blockIdx.x * ROWS;
    const long long row = rowbase + tid;

    // this thread's 4 spline inputs, one float4 load
    float xarr[GDIMS];
    {
        float4 xs = *(const float4*)(x + row * DD + ly0);
        xarr[0] = xs.x; xarr[1] = xs.y; xarr[2] = xs.z; xarr[3] = xs.w;
    }

    float zreg[GDIMS];
    float ldacc = 0.0f;

#pragma unroll
    for (int j = 0; j < GDIMS; ++j) {
        const int ly = ly0 + j;
        if (ly == 0) {
            float pr[NPAR];
#pragma unroll
            for (int k = 0; k < NPAR; ++k) pr[k] = p0[k];
            float ld;
            zreg[0] = rqs_apply(xarr[0], pr, ld);
            ldacc += ld;
            continue;
        }
        const int l = ly - 1;

        // ---- stage packed record (8192B = 512 int4) ----
        {
            const int4* src = (const int4*)(wbuf + (size_t)l * RECB);
            int4* dst = (int4*)sRec;
            dst[tid]       = src[tid];
            dst[tid + 256] = src[tid + 256];
        }
        __syncthreads();

        short8 w1a = *(const short8*)&sW1[ln * WST + q * 8];
        short8 w1b = *(const short8*)&sW1[(16 + ln) * WST + q * 8];
        short8 w2a = *(const short8*)&sW2[ln * WST + q * 8];
        short8 w2b = *(const short8*)&sW2[(16 + ln) * WST + q * 8];
        short8 w3a = *(const short8*)&sW3[ln * WST + q * 8];
        short8 w3b = *(const short8*)&sW3[(16 + ln) * WST + q * 8];
        float4 bA1 = *(const float4*)&sB1[4 * q];
        float4 bB1 = *(const float4*)&sB1[16 + 4 * q];
        float4 bA2 = *(const float4*)&sB2[4 * q];
        float4 bB2 = *(const float4*)&sB2[16 + 4 * q];
        float4 bA3 = *(const float4*)&sB3[4 * q];
        float4 bB3 = *(const float4*)&sB3[16 + 4 * q];

#pragma unroll
        for (int t = 0; t < 4; ++t) {
            const int m0 = 64 * wv + 16 * t;
            const float4* xp = (const float4*)(x + (rowbase + m0 + ln) * DD + q * 8);
            float4 uu = xp[0], vv = xp[1];
            union { int4 i; short8 s; } au;
            au.i = make_int4(pkbf(uu.x, uu.y), pkbf(uu.z, uu.w),
                             pkbf(vv.x, vv.y), pkbf(vv.z, vv.w));

            float4v cA = {0.f,0.f,0.f,0.f}, cB = {0.f,0.f,0.f,0.f};
            cA = __builtin_amdgcn_mfma_f32_16x16x32_bf16(w1a, au.s, cA, 0, 0, 0);
            cB = __builtin_amdgcn_mfma_f32_16x16x32_bf16(w1b, au.s, cB, 0, 0, 0);
            short8 h1f = xpose_h(cA, cB, bA1, bB1, qb, sl_a, sl_b, qlow);

            float4v dA = {0.f,0.f,0.f,0.f}, dB = {0.f,0.f,0.f,0.f};
            dA = __builtin_amdgcn_mfma_f32_16x16x32_bf16(w2a, h1f, dA, 0, 0, 0);
            dB = __builtin_amdgcn_mfma_f32_16x16x32_bf16(w2b, h1f, dB, 0, 0, 0);
            short8 h2f = xpose_h(dA, dB, bA2, bB2, qb, sl_a, sl_b, qlow);

            float4v eA = {0.f,0.f,0.f,0.f}, eB = {0.f,0.f,0.f,0.f};
            eA = __builtin_amdgcn_mfma_f32_16x16x32_bf16(w3a, h2f, eA, 0, 0, 0);
            eB = __builtin_amdgcn_mfma_f32_16x16x32_bf16(w3b, h2f, eB, 0, 0, 0);

            // params: row = batch col (m0+ln); lane holds outs 4q+r (eA) and
            // 16+4q+r (eB). eB for q>=2 is entirely junk (outs>=24) -> skip.
            int2 pv0 = make_int2(pkh(eA[0] + bA3.x, eA[1] + bA3.y),
                                 pkh(eA[2] + bA3.z, eA[3] + bA3.w));
            *(int2*)&sP[(m0 + ln) * PSTH + 4 * q] = pv0;
            if (qlow) {
                int2 pv1 = make_int2(pkh(eB[0] + bB3.x, eB[1] + bB3.y),
                                     pkh(eB[2] + bB3.z, eB[3] + bB3.w));
                *(int2*)&sP[(m0 + ln) * PSTH + 16 + 4 * q] = pv1;
            }
        }

        // ---- spline: thread tid -> row tid (written by OWN wave, lgkm-ordered)
        {
            half8v r0 = *(const half8v*)&sP[tid * PSTH];
            half8v r1 = *(const half8v*)&sP[tid * PSTH + 8];
            half8v r2 = *(const half8v*)&sP[tid * PSTH + 16];
            float pr[NPAR];
#pragma unroll
            for (int k = 0; k < 8; ++k) pr[k] = (float)r0[k];
#pragma unroll
            for (int k = 0; k < 8; ++k) pr[8 + k] = (float)r1[k];
#pragma unroll
            for (int k = 0; k < 7; ++k) pr[16 + k] = (float)r2[k];
            float ld;
            zreg[j] = rqs_apply(xarr[j], pr, ld);
            ldacc += ld;
        }
        __syncthreads();   // protect sRec/sP before next layer
    }

    float4 zv = make_float4(zreg[0], zreg[1], zreg[2], zreg[3]);
    *(float4*)(zo + row * DD + ly0) = zv;
    unsafeAtomicAdd(&ldo[row], ldacc);
}

extern "C" void kernel_launch(void* const* d_in, const int* in_sizes, int n_in,
                              void* d_out, int out_size, void* d_ws, size_t ws_size,
                              hipStream_t stream) {
    const float* x  = (const float*)d_in[0];
    const float* p0 = (const float*)d_in[1];
    const float* w1 = (const float*)d_in[2];
    const float* b1 = (const float*)d_in[3];
    const float* w2 = (const float*)d_in[4];
    const float* b2 = (const float*)d_in[5];
    const float* w3 = (const float*)d_in[6];
    const float* b3 = (const float*)d_in[7];

    const int B = in_sizes[0] / DD;            // 65536
    float* zo  = (float*)d_out;
    float* ldo = zo + (size_t)B * DD;
    char* wbuf = (char*)d_ws;                  // 31 * 8192 B = 254 KB

    hipLaunchKernelGGL(k_prep, dim3(31 + 64), dim3(256), 0, stream,
                       w1, b1, w2, b2, w3, b3, wbuf, ldo, B);
    hipLaunchKernelGGL(k_nsf, dim3(B / ROWS, DD / GDIMS), dim3(TPB), 0, stream,
                       x, p0, wbuf, zo, ldo, B);
}